// Round 16
// baseline (141.980 us; speedup 1.0000x reference)
//
#include <hip/hip_runtime.h>
#include <math.h>

#define Bn 16
#define Gn 2048
#define Cn 128
#define Kn 16
#define QB 32       // queries per block
#define SSEG 144    // padded+duplicated segment stride in float4 (128 pts + first 16 dup)
#define AS 136      // A/H-tile row stride in bf16 elems: 272B = 17*16B (aligned, 2-way banks)

typedef __attribute__((ext_vector_type(8))) short bf16x8;
typedef __attribute__((ext_vector_type(4))) float f32x4;

__device__ __forceinline__ unsigned short f2bf(float x) {   // RNE fp32->bf16
    unsigned int u = __float_as_uint(x);
    unsigned int r = (u + 0x7fffu + ((u >> 16) & 1u)) >> 16;
    return (unsigned short)r;
}
__device__ __forceinline__ float bf2f(unsigned short h) {
    return __uint_as_float(((unsigned int)h) << 16);
}

__device__ __forceinline__ float med3f(float a, float b, float c) {
#if __has_builtin(__builtin_amdgcn_fmed3f)
    return __builtin_amdgcn_fmed3f(a, b, c);
#else
    return fmaxf(fminf(a, b), fminf(fmaxf(a, b), c));
#endif
}

// BIT-IDENTICAL in every phase (fp-consistent ranking incl. tie detection).
__device__ __forceinline__ float dist2(const float4 me, const float4 p) {
    float dot = fmaf(me.z, p.z, fmaf(me.y, p.y, me.x * p.x));
    return fmaf(-2.0f, dot, me.w + p.w);
}

__device__ __forceinline__ void ins16(float (&d)[16], float v) {
    float prev = d[0];
    d[0] = fminf(d[0], v);
    #pragma unroll
    for (int t = 1; t < 16; ++t) { float cur = d[t]; d[t] = med3f(v, prev, cur); prev = cur; }
}

// exact bitonic min-merge of sorted d[16] across the 16 lanes of a group.
// In-place: pairs (t,15-t) disjoint; both shfl reads precede writes.
// ILP-wide (16 independent ops per stage) -- R14 lesson: serial shfl chains
// lose at low waves/SIMD even with fewer instructions.
__device__ __forceinline__ void merge16(float (&d)[16]) {
    #pragma unroll
    for (int m = 1; m < 16; m <<= 1) {
        #pragma unroll
        for (int t = 0; t < 8; ++t) {
            float sa = __shfl_xor(d[15 - t], m);    // partner's d[15-t]
            float sb = __shfl_xor(d[t], m);         // partner's d[t]
            d[t]      = fminf(d[t], sa);
            d[15 - t] = fminf(d[15 - t], sb);
        }
        #pragma unroll
        for (int k = 8; k; k >>= 1) {
            #pragma unroll
            for (int t = 0; t < 16; ++t)
                if (!(t & k)) {
                    float lo = fminf(d[t], d[t + k]);
                    float hi = fmaxf(d[t], d[t + k]);
                    d[t] = lo; d[t + k] = hi;
                }
        }
    }
}

__device__ __forceinline__ float gelu_exact(float x) {
    return 0.5f * x * (1.0f + erff(x * 0.70710678118654752440f));
}

// ---------------------------------------------------------------------------
// prep_w: W[k][n] fp32 -> Wt[n][k] split bf16 (hi/lo) in workspace.
// ws layout (ushorts): Wt1_hi[128*128] | Wt1_lo | Wt2_hi | Wt2_lo  (128 KB)
// ---------------------------------------------------------------------------
__global__ __launch_bounds__(256) void prep_w(const float* __restrict__ W1,
                                              const float* __restrict__ W2,
                                              unsigned short* __restrict__ ws) {
    int t = blockIdx.x * 256 + threadIdx.x;     // 0..16383 (grid 64)
    if (t < 16384) {
        int k = t >> 7, n = t & 127;
        float w = W1[t];
        unsigned short h = f2bf(w);
        unsigned short l = f2bf(w - bf2f(h));   // Dekker split: w-hi exact in fp32
        ws[n * 128 + k]          = h;
        ws[16384 + n * 128 + k]  = l;
        w = W2[t];
        h = f2bf(w);
        l = f2bf(w - bf2f(h));
        ws[32768 + n * 128 + k]  = h;
        ws[49152 + n * 128 + k]  = l;
    }
}

// ---------------------------------------------------------------------------
// Fully fused: KNN (sample->filter->select) + gather/L2-pool + MFMA MLP.
// 1024 blocks x 512 threads; b = x&15; chunk = x>>4 (0..63); 32 q/block.
// R16 = R15 base (best, 73us, VGPR 40, occ 49%) + 3 register-neutral
// instruction-class deletions:
//  (1) phase D: ballot-rounds (~270 ops) -> prefix-scan append (~110):
//      per-lane counts + shfl_up exclusive prefix + predicated writes.
//      Same index SET; outb order changes (pool sum order 1e-7 wiggle,
//      observed safe across R10/R11 reorders); tie-fill unchanged.
//  (2) gather: ushort4 index reads (8x ds_read_b64 vs 32x ds_read_u16);
//      neighbor accumulation order 0..15 unchanged (bit-identical pool).
//  (3) stage: 3x float4 loads/thread vs 12 scalar dwords.
// KNN core: wrap-free linear segment scan (SSEG=144, first-16 dup), T0 =
// exact 16th of 32 per-lane-top-2 candidates (conservative; phase C
// recovers exact T => output set exact). Register discipline: unroll<=4
// in scans (R13: full unroll -> 72 VGPR -> occupancy cliff).
// No min-waves bound (R4/R6: forcing it => 32/32 unified split + spills).
// MLP: single f32x4 acc, sequential col-blocks, H in separate LDS buffer;
// split-bf16 MFMA 16x16x32 (Ahi*Bhi + Ahi*Blo + Alo*Bhi, err ~2^-17).
// ---------------------------------------------------------------------------
__global__ __launch_bounds__(512) void fused_kernel(const float* __restrict__ xyz,
                                                    const float* __restrict__ feat,
                                                    const float* __restrict__ b1,
                                                    const float* __restrict__ b2,
                                                    const unsigned short* __restrict__ wt,
                                                    float* __restrict__ out) {
    __shared__ __align__(16) float smem0[9728];       // 38912 B
    float4* pts = reinterpret_cast<float4*>(smem0);   // [16][SSEG] padded (0..36864)
    unsigned short* Ahi = reinterpret_cast<unsigned short*>(smem0);  // [32][AS] 0..8704
    unsigned short* Alo = Ahi + QB * AS;                             // 8704..17408
    unsigned short* Hhi = Alo + QB * AS;                             // 17408..26112
    unsigned short* Hlo = Hhi + QB * AS;                             // 26112..34816
    unsigned short* outb = reinterpret_cast<unsigned short*>(smem0) + 18432;  // byte 36864, [32][16]
    unsigned short* tieb = outb + QB * 16;                                    // byte 37888, [32][16]
    // lifetimes: pts (stage..phase D) | outb/tieb (phase D..gather; above pts) |
    // Ahi/Alo (gather..L1, overlays dead pts) | Hhi/Hlo (L1..L2)

    const int x     = blockIdx.x;
    const int b     = x & 15;
    const int chunk = x >> 4;                       // 0..63
    const int tid   = threadIdx.x;                  // 0..511
    const int lane  = tid & 63;
    const int w     = tid >> 6;                     // 0..7
    const int sub   = lane & 15;                    // lane within 16-lane group
    const int qg    = lane >> 4;                    // query group within wave (0..3)
    const int q     = w * 4 + qg;                   // 0..31
    const int g     = chunk * QB + q;

    // ---- stage xyz + |p|^2: 4 points/thread via 3 float4 loads
    {
        const float4* xb4 = (const float4*)(xyz + (size_t)b * Gn * 3);
        float4 f0 = xb4[tid * 3 + 0];
        float4 f1 = xb4[tid * 3 + 1];
        float4 f2 = xb4[tid * 3 + 2];
        float px[4] = {f0.x, f0.w, f1.z, f2.y};
        float py[4] = {f0.y, f1.x, f1.w, f2.z};
        float pz[4] = {f0.z, f1.y, f2.x, f2.w};
        int i0 = tid * 4, sg = i0 >> 7, sl = i0 & 127;
        #pragma unroll
        for (int u = 0; u < 4; ++u) {
            float4 v = make_float4(px[u], py[u], pz[u],
                                   px[u] * px[u] + py[u] * py[u] + pz[u] * pz[u]);
            pts[sg * SSEG + sl + u] = v;
            if (sl + u < 16) pts[sg * SSEG + 128 + sl + u] = v;
        }
    }
    __syncthreads();

    const float4 me = pts[(g >> 7) * SSEG + (g & 127)];
    const float4* seg = pts + sub * SSEG + sub;     // lane's linear 128-pt window

    // ---- phase A: per-lane top-2 over first 32 window pts -> exact 16th of
    // 32 candidates -> conservative T0 (>= exact T; phase C recovers exact T)
    float m1 = INFINITY, m2 = INFINITY;
    #pragma unroll 4
    for (int j = 0; j < 32; ++j) {
        float v = dist2(me, seg[j]);
        m2 = med3f(v, m1, m2);                      // exact top-2 update
        m1 = fminf(m1, v);
    }
    float d[16];
    #pragma unroll
    for (int t = 2; t < 16; ++t) d[t] = INFINITY;
    d[0] = m1; d[1] = m2;                            // sorted ascending
    merge16(d);
    const float T0 = d[15];                          // 16th smallest of 32 cands

    // ---- phase B: filter scan -> register bitmask (bit p <-> window pt p)
    unsigned mw[4];
    #pragma unroll 1
    for (int wd = 0; wd < 4; ++wd) {
        unsigned mm = 0;
        #pragma unroll 4
        for (int j = 0; j < 32; ++j) {
            float v = dist2(me, seg[wd * 32 + j]);
            mm |= (v <= T0) ? (1u << j) : 0u;
        }
        mw[wd] = mm;
    }
    const unsigned long long blo = mw[0] | ((unsigned long long)mw[1] << 32);
    const unsigned long long bhi = mw[2] | ((unsigned long long)mw[3] << 32);

    // ---- phase C: exact top16 of survivors (own bits, no cross-lane) -> exact T
    #pragma unroll
    for (int t = 0; t < 16; ++t) d[t] = INFINITY;
    {
        unsigned long long m = blo;
        while (m) {
            int p = __builtin_ctzll(m); m &= m - 1;
            ins16(d, dist2(me, seg[p]));
        }
        m = bhi;
        while (m) {
            int p = 64 + __builtin_ctzll(m); m &= m - 1;
            ins16(d, dist2(me, seg[p]));
        }
    }
    merge16(d);
    const float T = d[15];

    // ---- phase D: emit index set via prefix-scan append (no ballot rounds)
    // pass 1: per-lane counts of (v<T) and (v==T) among own survivors
    int cntl = 0, cnte = 0;
    {
        unsigned long long m = blo;
        while (m) {
            int p = __builtin_ctzll(m); m &= m - 1;
            float v = dist2(me, seg[p]);
            cntl += (v < T); cnte += (v == T);
        }
        m = bhi;
        while (m) {
            int p = 64 + __builtin_ctzll(m); m &= m - 1;
            float v = dist2(me, seg[p]);
            cntl += (v < T); cnte += (v == T);
        }
    }
    // exclusive prefixes across the 16-lane group (Hillis-Steele, width 16)
    int il = cntl, ie = cnte;
    #pragma unroll
    for (int dlt = 1; dlt < 16; dlt <<= 1) {
        int yl = __shfl_up(il, dlt, 16);
        int ye = __shfl_up(ie, dlt, 16);
        if (sub >= dlt) { il += yl; ie += ye; }
    }
    int wl = il - cntl;                              // write cursor for v<T
    int we = ie - cnte;                              // write cursor for ties
    const int nl_tot = __shfl(il, 15, 16);           // total #(v<T) <= 15
    const int nt_tot = __shfl(ie, 15, 16);           // total ties
    // pass 2: append (set-exact; outb order is pool-order only)
    {
        unsigned long long m = blo;
        while (m) {
            int p = __builtin_ctzll(m); m &= m - 1;
            float v = dist2(me, seg[p]);
            int h = (sub << 7) | ((sub + p) & 127);
            if (v < T) outb[q * 16 + (wl++)] = (unsigned short)h;
            else if (v == T) { if (we < 16) tieb[q * 16 + we] = (unsigned short)h; we++; }
        }
        m = bhi;
        while (m) {
            int p = 64 + __builtin_ctzll(m); m &= m - 1;
            float v = dist2(me, seg[p]);
            int h = (sub << 7) | ((sub + p) & 127);
            if (v < T) outb[q * 16 + (wl++)] = (unsigned short)h;
            else if (v == T) { if (we < 16) tieb[q * 16 + we] = (unsigned short)h; we++; }
        }
    }
    if (sub == 0) {
        int mfill = nl_tot;                          // < 16
        int need  = 16 - mfill;
        int tc = (nt_tot > 16) ? 16 : nt_tot;
        for (int s = 0; s < need; ++s) {
            int best = 0x7fffffff, bp = -1;
            for (int u = 0; u < tc; ++u) {
                int vv = tieb[q * 16 + u];
                if (vv < best) { best = vv; bp = u; }
            }
            if (bp >= 0) { tieb[q * 16 + bp] = 0xFFFF; outb[q * 16 + mfill + s] = (unsigned short)best; }
        }
    }
    __syncthreads();                                 // pts dead; outb ready (above pts window)

    // ---- gather + L2 pool: half-wave per query, float4 lanes (512B coalesced)
    // ushort4 index reads; accumulation order = outb slots 0..15 sequentially.
    const float4* fb4 = (const float4*)(feat + (size_t)b * Gn * Cn);
    const int cll = lane & 31;
    #pragma unroll
    for (int pass = 0; pass < 2; ++pass) {
        int qq = w * 4 + pass * 2 + (lane >> 5);
        float4 a = make_float4(0.f, 0.f, 0.f, 0.f);
        #pragma unroll
        for (int qt = 0; qt < 4; ++qt) {
            ushort4 h4 = *(const ushort4*)&outb[qq * 16 + qt * 4];
            float4 f0 = fb4[(size_t)h4.x * 32 + cll];
            float4 f1 = fb4[(size_t)h4.y * 32 + cll];
            a.x = fmaf(f0.x, f0.x, a.x); a.y = fmaf(f0.y, f0.y, a.y);
            a.z = fmaf(f0.z, f0.z, a.z); a.w = fmaf(f0.w, f0.w, a.w);
            a.x = fmaf(f1.x, f1.x, a.x); a.y = fmaf(f1.y, f1.y, a.y);
            a.z = fmaf(f1.z, f1.z, a.z); a.w = fmaf(f1.w, f1.w, a.w);
            float4 f2 = fb4[(size_t)h4.z * 32 + cll];
            float4 f3 = fb4[(size_t)h4.w * 32 + cll];
            a.x = fmaf(f2.x, f2.x, a.x); a.y = fmaf(f2.y, f2.y, a.y);
            a.z = fmaf(f2.z, f2.z, a.z); a.w = fmaf(f2.w, f2.w, a.w);
            a.x = fmaf(f3.x, f3.x, a.x); a.y = fmaf(f3.y, f3.y, a.y);
            a.z = fmaf(f3.z, f3.z, a.z); a.w = fmaf(f3.w, f3.w, a.w);
        }
        float r0 = sqrtf(a.x), r1 = sqrtf(a.y), r2 = sqrtf(a.z), r3 = sqrtf(a.w);
        unsigned short h0 = f2bf(r0), h1 = f2bf(r1), h2 = f2bf(r2), h3 = f2bf(r3);
        ushort4 hv = make_ushort4(h0, h1, h2, h3);
        ushort4 lv = make_ushort4(f2bf(r0 - bf2f(h0)), f2bf(r1 - bf2f(h1)),
                                  f2bf(r2 - bf2f(h2)), f2bf(r3 - bf2f(h3)));
        *(ushort4*)&Ahi[qq * AS + cll * 4] = hv;
        *(ushort4*)&Alo[qq * AS + cll * 4] = lv;
    }
    __syncthreads();                                 // A ready; outb/tieb dead

    // ---- MLP via split-bf16 MFMA, ONE f32x4 acc (sequential col-blocks) ----
    // wave w: rows rowg..rowg+15 (rowg=(w&1)*16), cols colg0..colg0+31
    // A-frag: lane l -> A[rowg+(l&15)][kk + (l>>4)*8 + j]  (contiguous bf16x8)
    // B-frag: lane l -> Wt[colg0+cb*16+(l&15)][kk + (l>>4)*8 + j] (contiguous)
    // C/D:    lane l, reg r -> C[(l>>4)*4 + r][l&15]   (m89-verified)
    const int l15  = lane & 15;
    const int kofs = (lane >> 4) * 8;
    const int rowg = (w & 1) * 16;
    const int colg0 = (w >> 1) * 32;

    // ---- layer 1: H = gelu(A @ W1 + b1) -> Hhi/Hlo (separate buffer, no alias)
    #pragma unroll 1
    for (int cb = 0; cb < 2; ++cb) {
        float bv = b1[colg0 + cb * 16 + l15];
        f32x4 acc = (f32x4){bv, bv, bv, bv};
        #pragma unroll
        for (int kk = 0; kk < 128; kk += 32) {
            bf16x8 ah = *(const bf16x8*)&Ahi[(rowg + l15) * AS + kk + kofs];
            bf16x8 al = *(const bf16x8*)&Alo[(rowg + l15) * AS + kk + kofs];
            const unsigned short* wp = wt + (size_t)(colg0 + cb * 16 + l15) * 128 + kk + kofs;
            bf16x8 bh = *(const bf16x8*)wp;
            bf16x8 bl = *(const bf16x8*)(wp + 16384);
            acc = __builtin_amdgcn_mfma_f32_16x16x32_bf16(ah, bh, acc, 0, 0, 0);
            acc = __builtin_amdgcn_mfma_f32_16x16x32_bf16(ah, bl, acc, 0, 0, 0);
            acc = __builtin_amdgcn_mfma_f32_16x16x32_bf16(al, bh, acc, 0, 0, 0);
        }
        #pragma unroll
        for (int r = 0; r < 4; ++r) {
            float gv = gelu_exact(acc[r]);
            unsigned short h = f2bf(gv);
            int row = rowg + (lane >> 4) * 4 + r;
            int col = colg0 + cb * 16 + l15;
            Hhi[row * AS + col] = h;
            Hlo[row * AS + col] = f2bf(gv - bf2f(h));
        }
    }
    __syncthreads();                            // H tile complete (all waves)

    // ---- layer 2: out = H @ W2 + b2 (store each col-block directly)
    const size_t orow0 = (size_t)b * Gn + (size_t)chunk * QB + rowg + (lane >> 4) * 4;
    #pragma unroll 1
    for (int cb = 0; cb < 2; ++cb) {
        float bv = b2[colg0 + cb * 16 + l15];
        f32x4 acc = (f32x4){bv, bv, bv, bv};
        #pragma unroll
        for (int kk = 0; kk < 128; kk += 32) {
            bf16x8 ah = *(const bf16x8*)&Hhi[(rowg + l15) * AS + kk + kofs];
            bf16x8 al = *(const bf16x8*)&Hlo[(rowg + l15) * AS + kk + kofs];
            const unsigned short* wp = wt + 32768 + (size_t)(colg0 + cb * 16 + l15) * 128 + kk + kofs;
            bf16x8 bh = *(const bf16x8*)wp;
            bf16x8 bl = *(const bf16x8*)(wp + 16384);
            acc = __builtin_amdgcn_mfma_f32_16x16x32_bf16(ah, bh, acc, 0, 0, 0);
            acc = __builtin_amdgcn_mfma_f32_16x16x32_bf16(ah, bl, acc, 0, 0, 0);
            acc = __builtin_amdgcn_mfma_f32_16x16x32_bf16(al, bh, acc, 0, 0, 0);
        }
        #pragma unroll
        for (int r = 0; r < 4; ++r) {
            out[(orow0 + r) * Cn + colg0 + cb * 16 + l15] = acc[r];
        }
    }
}

// ---------------------------------------------------------------------------
extern "C" void kernel_launch(void* const* d_in, const int* in_sizes, int n_in,
                              void* d_out, int out_size, void* d_ws, size_t ws_size,
                              hipStream_t stream) {
    const float* xyz  = (const float*)d_in[0];
    const float* feat = (const float*)d_in[1];
    const float* W1   = (const float*)d_in[2];
    const float* b1   = (const float*)d_in[3];
    const float* W2   = (const float*)d_in[4];
    const float* b2   = (const float*)d_in[5];
    float* out = (float*)d_out;
    unsigned short* wt = (unsigned short*)d_ws;    // 128 KB: Wt1 hi/lo, Wt2 hi/lo

    prep_w<<<64, 256, 0, stream>>>(W1, W2, wt);
    fused_kernel<<<1024, 512, 0, stream>>>(xyz, feat, b1, b2, wt, out);
}